// Round 8
// baseline (161.493 us; speedup 1.0000x reference)
//
#include <hip/hip_runtime.h>
#include <hip/hip_bf16.h>

#define BB 16
#define NQ 64
#define NK 512
#define HD 256   // H = QS = KS = VD = 256

typedef __attribute__((ext_vector_type(8))) short short8;
typedef __attribute__((ext_vector_type(4))) float f32x4;

__device__ __forceinline__ ushort bf16_rne(float v) {
    unsigned u = __float_as_uint(v);
    return (ushort)((u + 0x7FFFu + ((u >> 16) & 1u)) >> 16);
}
__device__ __forceinline__ float bf16_to_f(ushort h) {
    return __uint_as_float(((unsigned)h) << 16);
}

// ---------------------------------------------------------------------------
// Projection GEMM with FUSED A-conversion AND FUSED W-conversion (wconv
// kernel deleted: each block gathers its W fp32 slice [k][cols0+sr] -- 
// coalesced across lanes per k-row, L2-resident after first touch -- and
// splits to hi/lo bf16 in registers, bit-identical to the old wconv path).
// C = AhWh + AlWh + AhWl; epilogue exp2(acc*scale) so the score kernel
// consumes EQ=e^{2q}, EK=e^{2k} directly.  Tile 64x64, BK=64, 576 blocks.
// ---------------------------------------------------------------------------
__global__ __launch_bounds__(256, 2) void proj_fused2(
    const float* __restrict__ queries, const float* __restrict__ keys,
    const float* __restrict__ W_q, const float* __restrict__ W_k,
    float* __restrict__ qp, float* __restrict__ kp, float scale)
{
    __shared__ ushort AsH[64 * 64], AsL[64 * 64];
    __shared__ ushort BsH[64 * 64], BsL[64 * 64];

    const float* A; const float* W; float* C; int rows0;
    const int bx = blockIdx.x;
    if (bx < 16) { A = queries; W = W_q; C = qp; rows0 = bx * 64; }
    else         { A = keys;    W = W_k; C = kp; rows0 = (bx - 16) * 64; }
    const int cols0 = blockIdx.y * 64;

    const int t = threadIdx.x, lane = t & 63, wave = t >> 6;
    const int quad = lane >> 4, l15 = lane & 15;
    const int sr  = t >> 2;          // staging row / n: 0..63
    const int sc2 = (t & 3) * 2;     // chunk pair base: 0,2,4,6

    f32x4 acc[4];
    #pragma unroll
    for (int j = 0; j < 4; ++j) acc[j] = (f32x4){0.f, 0.f, 0.f, 0.f};

    for (int k0 = 0; k0 < 256; k0 += 64) {
        // global loads: A fp32 (16 elems), W fp32 gathered [k][cols0+sr]
        const float* arow = &A[(size_t)(rows0 + sr) * 256 + k0 + sc2 * 8];
        float4 a0 = *(const float4*)&arow[0];
        float4 a1 = *(const float4*)&arow[4];
        float4 a2 = *(const float4*)&arow[8];
        float4 a3 = *(const float4*)&arow[12];
        float wvv[16];
        {
            const float* wsrc = &W[(size_t)(k0 + sc2 * 8) * 256 + cols0 + sr];
            #pragma unroll
            for (int e = 0; e < 16; ++e)
                wvv[e] = wsrc[(size_t)e * 256];
        }

        __syncthreads();   // previous tile's compute done

        // convert A and W to hi/lo bf16 in registers
        float av[16] = {a0.x, a0.y, a0.z, a0.w, a1.x, a1.y, a1.z, a1.w,
                        a2.x, a2.y, a2.z, a2.w, a3.x, a3.y, a3.z, a3.w};
        short8 ah0, ah1, al0, al1, bh0, bh1, bl0, bl1;
        #pragma unroll
        for (int e = 0; e < 8; ++e) {
            ushort h0 = bf16_rne(av[e]);
            ushort h1 = bf16_rne(av[8 + e]);
            ah0[e] = (short)h0;
            ah1[e] = (short)h1;
            al0[e] = (short)bf16_rne(av[e] - bf16_to_f(h0));
            al1[e] = (short)bf16_rne(av[8 + e] - bf16_to_f(h1));
            ushort w0 = bf16_rne(wvv[e]);
            ushort w1 = bf16_rne(wvv[8 + e]);
            bh0[e] = (short)w0;
            bh1[e] = (short)w1;
            bl0[e] = (short)bf16_rne(wvv[e] - bf16_to_f(w0));
            bl1[e] = (short)bf16_rne(wvv[8 + e] - bf16_to_f(w1));
        }
        // XOR-swizzled LDS stores (chunk slot = c ^ (row&7))
        {
            int s0 = sr * 8 + ((sc2 + 0) ^ (sr & 7));
            int s1 = sr * 8 + ((sc2 + 1) ^ (sr & 7));
            *(short8*)&AsH[s0 * 8] = ah0;
            *(short8*)&AsH[s1 * 8] = ah1;
            *(short8*)&AsL[s0 * 8] = al0;
            *(short8*)&AsL[s1 * 8] = al1;
            *(short8*)&BsH[s0 * 8] = bh0;
            *(short8*)&BsH[s1 * 8] = bh1;
            *(short8*)&BsL[s0 * 8] = bl0;
            *(short8*)&BsL[s1 * 8] = bl1;
        }
        __syncthreads();

        #pragma unroll
        for (int ks = 0; ks < 2; ++ks) {
            const int c = ks * 4 + quad;
            short8 aH, aL, bH[4], bL[4];
            {
                int r = wave * 16 + l15;
                int slot = r * 8 + (c ^ (r & 7));
                aH = *(const short8*)&AsH[slot * 8];
                aL = *(const short8*)&AsL[slot * 8];
            }
            #pragma unroll
            for (int ns = 0; ns < 4; ++ns) {
                int n = ns * 16 + l15;
                int slot = n * 8 + (c ^ (n & 7));
                bH[ns] = *(const short8*)&BsH[slot * 8];
                bL[ns] = *(const short8*)&BsL[slot * 8];
            }
            #pragma unroll
            for (int ns = 0; ns < 4; ++ns)
                acc[ns] = __builtin_amdgcn_mfma_f32_16x16x32_bf16(aH, bH[ns], acc[ns], 0, 0, 0);
            #pragma unroll
            for (int ns = 0; ns < 4; ++ns)
                acc[ns] = __builtin_amdgcn_mfma_f32_16x16x32_bf16(aL, bH[ns], acc[ns], 0, 0, 0);
            #pragma unroll
            for (int ns = 0; ns < 4; ++ns)
                acc[ns] = __builtin_amdgcn_mfma_f32_16x16x32_bf16(aH, bL[ns], acc[ns], 0, 0, 0);
        }
    }

    // epilogue: C/D col=lane&15, row=quad*4+reg.  Store exp2(x*scale).
    const int rbase = rows0 + wave * 16 + quad * 4;
    #pragma unroll
    for (int ns = 0; ns < 4; ++ns) {
        int col = cols0 + ns * 16 + l15;
        #pragma unroll
        for (int r = 0; r < 4; ++r)
            C[(size_t)(rbase + r) * 256 + col] =
                __builtin_amdgcn_exp2f(acc[ns][r] * scale);
    }
}

// ---------------------------------------------------------------------------
// score_a: PURE score kernel (unchanged from round 7).  Block = (b,qt8,seg64),
// 1024 blocks, 256 thr, ONE barrier.  Writes Pt[b][k][64q] = e^{score}
// (no-max softmax numerator, masked -> 0).  LDS 9.3 KB -> ~16 waves/CU.
// ---------------------------------------------------------------------------
__global__ __launch_bounds__(256, 4) void score_a(
    const float* __restrict__ qp,      // [B*NQ, H]  EQ = exp2(q * 2/ln2)
    const float* __restrict__ kp,      // [B*NK, H]  EK = exp2(k * 2/ln2)
    const int*   __restrict__ vlens,   // [B]
    const float* __restrict__ w_v,     // [H]
    float* __restrict__ Pt)            // [B][NK][64]  P^T
{
    __shared__ float eq[8][260];
    __shared__ float wv[HD];

    const int b   = blockIdx.x & 15;
    const int qt  = blockIdx.x >> 4;    // 0..7
    const int seg = blockIdx.y;         // 0..7
    const int vl  = vlens[b];
    if (seg * 64 >= vl) return;

    const int t = threadIdx.x, lane = t & 63, wave = t >> 6;
    const int key = wave * 16 + (lane >> 2);   // 0..63
    const int ch  = lane & 3;
    const int kg  = seg * 64 + key;

    // prefetch full ek row (16 float4); drains at the one barrier below,
    // overlapped with the eq/wv staging loads.
    const float* krow = kp + ((size_t)b * NK + kg) * HD + ch * 4;
    float4 ek[16];
    #pragma unroll
    for (int j = 0; j < 16; ++j) ek[j] = *(const float4*)&krow[j * 16];

    const float* qsrc = qp + ((size_t)b * NQ + qt * 8) * HD;
    #pragma unroll
    for (int i = 0; i < 2; ++i) {
        int idx = i * 256 + t;
        int row = idx >> 6, c4 = (idx & 63) * 4;
        *(float4*)&eq[row][c4] = *(const float4*)&qsrc[(size_t)row * HD + c4];
    }
    if (t < 64) *(float4*)&wv[t * 4] = *(const float4*)&w_v[t * 4];
    __syncthreads();

    float Wsum;
    {
        float ws = wv[lane] + wv[lane + 64] + wv[lane + 128] + wv[lane + 192];
        #pragma unroll
        for (int off = 32; off; off >>= 1) ws += __shfl_xor(ws, off);
        Wsum = ws;
    }

    // scores: 4-way grouped reciprocal, ek from regs, eq/wv LDS broadcast
    float s[8] = {0.f, 0.f, 0.f, 0.f, 0.f, 0.f, 0.f, 0.f};
    #pragma unroll
    for (int j = 0; j < 16; ++j) {
        const int h = j * 16 + ch * 4;
        float4 e4 = ek[j];
        float4 w4 = *(const float4*)&wv[h];
        #pragma unroll
        for (int qi = 0; qi < 8; ++qi) {
            float4 q4 = *(const float4*)&eq[qi][h];
            float p0 = fmaf(q4.x, e4.x, 1.f);
            float p1 = fmaf(q4.y, e4.y, 1.f);
            float p2 = fmaf(q4.z, e4.z, 1.f);
            float p3 = fmaf(q4.w, e4.w, 1.f);
            float d01 = p0 * p1;
            float d23 = p2 * p3;
            float n01 = fmaf(w4.x, p1, w4.y * p0);
            float n23 = fmaf(w4.z, p3, w4.w * p2);
            float num = fmaf(d01, n23, d23 * n01);
            float r   = __builtin_amdgcn_rcpf(d01 * d23);
            s[qi] = fmaf(num, r, s[qi]);
        }
    }
    #pragma unroll
    for (int qi = 0; qi < 8; ++qi) {
        s[qi] += __shfl_xor(s[qi], 1);
        s[qi] += __shfl_xor(s[qi], 2);
    }

    if (ch == 0) {
        const bool masked = (kg >= vl);
        const float L2E = 1.4426950408889634f;
        float pt[8];
        #pragma unroll
        for (int qi = 0; qi < 8; ++qi) {
            float sv = fmaf(-2.f, s[qi], Wsum);      // |score| <= ~13
            pt[qi] = masked ? 0.f : __builtin_amdgcn_exp2f(sv * L2E);
        }
        float* dst = &Pt[((size_t)b * NK + kg) * 64 + qt * 8];
        *(float4*)&dst[0] = make_float4(pt[0], pt[1], pt[2], pt[3]);
        *(float4*)&dst[4] = make_float4(pt[4], pt[5], pt[6], pt[7]);
    }
}

// ---------------------------------------------------------------------------
// pv_b2: O = P.V streaming GEMM fused with L = sum_k p and the division.
// Grid 512 = (b | qt8 | vd64-quarter); b in low bits -> same-b blocks land on
// the same XCD (bx%8 = b%8) so V[b] (512 KB) stays L2-resident.
// HAND-WRITTEN 8-deep ring pipeline (vr/pr): 16 vmem in flight, NO barriers
// in the k-loop -- immune to the runtime-bound-unroll codegen failure that
// likely left round-7's pv_b as a 1-deep ~230cyc/iter latency chain.
// Per-thread trip count nk/2 is a multiple of 32 -> ring needs no tail.
// ---------------------------------------------------------------------------
__global__ __launch_bounds__(256) void pv_b2(
    const float* __restrict__ Pt,      // [B][NK][64]
    const float* __restrict__ values,  // [B][NK][256]
    const int*   __restrict__ vlens,
    float* __restrict__ out)           // [B*NQ, 256]
{
    __shared__ f32x4 red[128];
    __shared__ float Lred[8];
    __shared__ float Lfin[8];

    const int bx  = blockIdx.x;
    const int b   = bx & 15;
    const int qt  = (bx >> 4) & 7;
    const int vdq = bx >> 7;            // 0..3
    const int vl  = vlens[b];
    const int nk  = ((vl + 63) >> 6) << 6;   // alive keys, seg-rounded

    const int t   = threadIdx.x;
    const int vd4 = t & 15;
    const int q   = (t >> 4) & 7;
    const int kp2 = t >> 7;             // 0..1

    const float* vptr = values + (size_t)b * NK * HD + vdq * 64 + vd4 * 4;
    const float* pptr = Pt + (size_t)b * NK * 64 + qt * 8 + q;

    f32x4 acc = (f32x4){0.f, 0.f, 0.f, 0.f};
    float Lacc = 0.f;

    const int iters = nk >> 1;          // per-thread k-pairs: 32..256, %32==0
    float4 vr[8];
    float  pr[8];
    #pragma unroll
    for (int i = 0; i < 8; ++i) {
        int k = kp2 + 2 * i;
        pr[i] = pptr[(size_t)k * 64];
        vr[i] = *(const float4*)&vptr[(size_t)k * HD];
    }
    int base = 8;
    while (true) {
        const bool more = base < iters;
        #pragma unroll
        for (int i = 0; i < 8; ++i) {
            float  p = pr[i];
            float4 v = vr[i];
            if (more) {
                int k = kp2 + 2 * (base + i);
                pr[i] = pptr[(size_t)k * 64];
                vr[i] = *(const float4*)&vptr[(size_t)k * HD];
            }
            acc[0] = fmaf(p, v.x, acc[0]);
            acc[1] = fmaf(p, v.y, acc[1]);
            acc[2] = fmaf(p, v.z, acc[2]);
            acc[3] = fmaf(p, v.w, acc[3]);
            Lacc += p;
        }
        if (!more) break;
        base += 8;
    }

    if (kp2 == 1) {
        red[t - 128] = acc;
        if (vd4 == 0) Lred[q] = Lacc;
    }
    __syncthreads();
    if (kp2 == 0) {
        f32x4 o = red[t];
        acc[0] += o[0]; acc[1] += o[1]; acc[2] += o[2]; acc[3] += o[3];
        if (vd4 == 0) Lfin[q] = Lacc + Lred[q];
    }
    __syncthreads();
    if (kp2 == 0) {
        float r = __builtin_amdgcn_rcpf(Lfin[q]);
        float4 o = make_float4(acc[0] * r, acc[1] * r, acc[2] * r, acc[3] * r);
        *(float4*)&out[((size_t)(b * 64 + qt * 8 + q)) * 256 + vdq * 64 + vd4 * 4] = o;
    }
}

extern "C" void kernel_launch(void* const* d_in, const int* in_sizes, int n_in,
                              void* d_out, int out_size, void* d_ws, size_t ws_size,
                              hipStream_t stream) {
    const float* queries = (const float*)d_in[0];
    const float* keys    = (const float*)d_in[1];
    const float* values  = (const float*)d_in[2];
    const int*   vlens   = (const int*)d_in[3];
    const float* W_q     = (const float*)d_in[4];
    const float* W_k     = (const float*)d_in[5];
    const float* w_v     = (const float*)d_in[6];
    float* out = (float*)d_out;

    // ws layout (~11 MB of 256 MiB):
    float* kp = (float*)d_ws;                            // 8 MB
    float* qp = kp + (size_t)BB * NK * HD;               // 1 MB
    float* Pt = qp + (size_t)BB * NQ * HD;               // 2 MB  [B][NK][64]

    const float SC = 2.885390081777927f;                 // 2/ln(2)

    proj_fused2<<<dim3(144, 4), 256, 0, stream>>>(queries, keys, W_q, W_k,
                                                  qp, kp, SC);
    score_a<<<dim3(128, 8), 256, 0, stream>>>(qp, kp, vlens, w_v, Pt);
    pv_b2<<<dim3(512), 256, 0, stream>>>(Pt, values, vlens, out);
}

// Round 9
// 125.334 us; speedup vs baseline: 1.2885x; 1.2885x over previous
//
#include <hip/hip_runtime.h>
#include <hip/hip_bf16.h>

#define BB 16
#define NQ 64
#define NK 512
#define HD 256   // H = QS = KS = VD = 256

typedef __attribute__((ext_vector_type(8))) short short8;
typedef __attribute__((ext_vector_type(4))) float f32x4;

__device__ __forceinline__ ushort bf16_rne(float v) {
    unsigned u = __float_as_uint(v);
    return (ushort)((u + 0x7FFFu + ((u >> 16) & 1u)) >> 16);
}
__device__ __forceinline__ float bf16_to_f(ushort h) {
    return __uint_as_float(((unsigned)h) << 16);
}

// ---------------------------------------------------------------------------
// Projection GEMM with FUSED A-conversion AND FUSED W-conversion (unchanged
// from round 8).  epilogue exp2(acc*scale): score kernel consumes EQ/EK.
// ---------------------------------------------------------------------------
__global__ __launch_bounds__(256, 2) void proj_fused2(
    const float* __restrict__ queries, const float* __restrict__ keys,
    const float* __restrict__ W_q, const float* __restrict__ W_k,
    float* __restrict__ qp, float* __restrict__ kp, float scale)
{
    __shared__ ushort AsH[64 * 64], AsL[64 * 64];
    __shared__ ushort BsH[64 * 64], BsL[64 * 64];

    const float* A; const float* W; float* C; int rows0;
    const int bx = blockIdx.x;
    if (bx < 16) { A = queries; W = W_q; C = qp; rows0 = bx * 64; }
    else         { A = keys;    W = W_k; C = kp; rows0 = (bx - 16) * 64; }
    const int cols0 = blockIdx.y * 64;

    const int t = threadIdx.x, lane = t & 63, wave = t >> 6;
    const int quad = lane >> 4, l15 = lane & 15;
    const int sr  = t >> 2;          // staging row / n: 0..63
    const int sc2 = (t & 3) * 2;     // chunk pair base: 0,2,4,6

    f32x4 acc[4];
    #pragma unroll
    for (int j = 0; j < 4; ++j) acc[j] = (f32x4){0.f, 0.f, 0.f, 0.f};

    for (int k0 = 0; k0 < 256; k0 += 64) {
        const float* arow = &A[(size_t)(rows0 + sr) * 256 + k0 + sc2 * 8];
        float4 a0 = *(const float4*)&arow[0];
        float4 a1 = *(const float4*)&arow[4];
        float4 a2 = *(const float4*)&arow[8];
        float4 a3 = *(const float4*)&arow[12];
        float wvv[16];
        {
            const float* wsrc = &W[(size_t)(k0 + sc2 * 8) * 256 + cols0 + sr];
            #pragma unroll
            for (int e = 0; e < 16; ++e)
                wvv[e] = wsrc[(size_t)e * 256];
        }

        __syncthreads();   // previous tile's compute done

        float av[16] = {a0.x, a0.y, a0.z, a0.w, a1.x, a1.y, a1.z, a1.w,
                        a2.x, a2.y, a2.z, a2.w, a3.x, a3.y, a3.z, a3.w};
        short8 ah0, ah1, al0, al1, bh0, bh1, bl0, bl1;
        #pragma unroll
        for (int e = 0; e < 8; ++e) {
            ushort h0 = bf16_rne(av[e]);
            ushort h1 = bf16_rne(av[8 + e]);
            ah0[e] = (short)h0;
            ah1[e] = (short)h1;
            al0[e] = (short)bf16_rne(av[e] - bf16_to_f(h0));
            al1[e] = (short)bf16_rne(av[8 + e] - bf16_to_f(h1));
            ushort w0 = bf16_rne(wvv[e]);
            ushort w1 = bf16_rne(wvv[8 + e]);
            bh0[e] = (short)w0;
            bh1[e] = (short)w1;
            bl0[e] = (short)bf16_rne(wvv[e] - bf16_to_f(w0));
            bl1[e] = (short)bf16_rne(wvv[8 + e] - bf16_to_f(w1));
        }
        {
            int s0 = sr * 8 + ((sc2 + 0) ^ (sr & 7));
            int s1 = sr * 8 + ((sc2 + 1) ^ (sr & 7));
            *(short8*)&AsH[s0 * 8] = ah0;
            *(short8*)&AsH[s1 * 8] = ah1;
            *(short8*)&AsL[s0 * 8] = al0;
            *(short8*)&AsL[s1 * 8] = al1;
            *(short8*)&BsH[s0 * 8] = bh0;
            *(short8*)&BsH[s1 * 8] = bh1;
            *(short8*)&BsL[s0 * 8] = bl0;
            *(short8*)&BsL[s1 * 8] = bl1;
        }
        __syncthreads();

        #pragma unroll
        for (int ks = 0; ks < 2; ++ks) {
            const int c = ks * 4 + quad;
            short8 aH, aL, bH[4], bL[4];
            {
                int r = wave * 16 + l15;
                int slot = r * 8 + (c ^ (r & 7));
                aH = *(const short8*)&AsH[slot * 8];
                aL = *(const short8*)&AsL[slot * 8];
            }
            #pragma unroll
            for (int ns = 0; ns < 4; ++ns) {
                int n = ns * 16 + l15;
                int slot = n * 8 + (c ^ (n & 7));
                bH[ns] = *(const short8*)&BsH[slot * 8];
                bL[ns] = *(const short8*)&BsL[slot * 8];
            }
            #pragma unroll
            for (int ns = 0; ns < 4; ++ns)
                acc[ns] = __builtin_amdgcn_mfma_f32_16x16x32_bf16(aH, bH[ns], acc[ns], 0, 0, 0);
            #pragma unroll
            for (int ns = 0; ns < 4; ++ns)
                acc[ns] = __builtin_amdgcn_mfma_f32_16x16x32_bf16(aL, bH[ns], acc[ns], 0, 0, 0);
            #pragma unroll
            for (int ns = 0; ns < 4; ++ns)
                acc[ns] = __builtin_amdgcn_mfma_f32_16x16x32_bf16(aH, bL[ns], acc[ns], 0, 0, 0);
        }
    }

    const int rbase = rows0 + wave * 16 + quad * 4;
    #pragma unroll
    for (int ns = 0; ns < 4; ++ns) {
        int col = cols0 + ns * 16 + l15;
        #pragma unroll
        for (int r = 0; r < 4; ++r)
            C[(size_t)(rbase + r) * 256 + col] =
                __builtin_amdgcn_exp2f(acc[ns][r] * scale);
    }
}

// ---------------------------------------------------------------------------
// score_a2: PURE score kernel.  Same as round 7/8 EXCEPT dead-segment blocks
// now ZERO-FILL their Pt slice (instead of leaving poison) so pv_c can run a
// compile-time 512-key loop with p=0 beyond vl.  Masked keys in live
// segments already write 0.  Live path bit-identical to round 8.
// ---------------------------------------------------------------------------
__global__ __launch_bounds__(256, 4) void score_a2(
    const float* __restrict__ qp,      // [B*NQ, H]  EQ = exp2(q * 2/ln2)
    const float* __restrict__ kp,      // [B*NK, H]  EK = exp2(k * 2/ln2)
    const int*   __restrict__ vlens,   // [B]
    const float* __restrict__ w_v,     // [H]
    float* __restrict__ Pt)            // [B][NK][64]  P^T
{
    __shared__ float eq[8][260];
    __shared__ float wv[HD];

    const int b   = blockIdx.x & 15;
    const int qt  = blockIdx.x >> 4;    // 0..7
    const int seg = blockIdx.y;         // 0..7
    const int vl  = vlens[b];

    const int t = threadIdx.x, lane = t & 63, wave = t >> 6;
    const int key = wave * 16 + (lane >> 2);   // 0..63
    const int ch  = lane & 3;
    const int kg  = seg * 64 + key;

    if (seg * 64 >= vl) {
        // dead segment: define Pt = 0 so pv_c's static 512-key loop is exact
        if (ch == 0) {
            float* dst = &Pt[((size_t)b * NK + kg) * 64 + qt * 8];
            *(float4*)&dst[0] = make_float4(0.f, 0.f, 0.f, 0.f);
            *(float4*)&dst[4] = make_float4(0.f, 0.f, 0.f, 0.f);
        }
        return;
    }

    // prefetch full ek row (16 float4); drains at the one barrier below,
    // overlapped with the eq/wv staging loads.
    const float* krow = kp + ((size_t)b * NK + kg) * HD + ch * 4;
    float4 ek[16];
    #pragma unroll
    for (int j = 0; j < 16; ++j) ek[j] = *(const float4*)&krow[j * 16];

    const float* qsrc = qp + ((size_t)b * NQ + qt * 8) * HD;
    #pragma unroll
    for (int i = 0; i < 2; ++i) {
        int idx = i * 256 + t;
        int row = idx >> 6, c4 = (idx & 63) * 4;
        *(float4*)&eq[row][c4] = *(const float4*)&qsrc[(size_t)row * HD + c4];
    }
    if (t < 64) *(float4*)&wv[t * 4] = *(const float4*)&w_v[t * 4];
    __syncthreads();

    float Wsum;
    {
        float ws = wv[lane] + wv[lane + 64] + wv[lane + 128] + wv[lane + 192];
        #pragma unroll
        for (int off = 32; off; off >>= 1) ws += __shfl_xor(ws, off);
        Wsum = ws;
    }

    // scores: 4-way grouped reciprocal, ek from regs, eq/wv LDS broadcast
    float s[8] = {0.f, 0.f, 0.f, 0.f, 0.f, 0.f, 0.f, 0.f};
    #pragma unroll
    for (int j = 0; j < 16; ++j) {
        const int h = j * 16 + ch * 4;
        float4 e4 = ek[j];
        float4 w4 = *(const float4*)&wv[h];
        #pragma unroll
        for (int qi = 0; qi < 8; ++qi) {
            float4 q4 = *(const float4*)&eq[qi][h];
            float p0 = fmaf(q4.x, e4.x, 1.f);
            float p1 = fmaf(q4.y, e4.y, 1.f);
            float p2 = fmaf(q4.z, e4.z, 1.f);
            float p3 = fmaf(q4.w, e4.w, 1.f);
            float d01 = p0 * p1;
            float d23 = p2 * p3;
            float n01 = fmaf(w4.x, p1, w4.y * p0);
            float n23 = fmaf(w4.z, p3, w4.w * p2);
            float num = fmaf(d01, n23, d23 * n01);
            float r   = __builtin_amdgcn_rcpf(d01 * d23);
            s[qi] = fmaf(num, r, s[qi]);
        }
    }
    #pragma unroll
    for (int qi = 0; qi < 8; ++qi) {
        s[qi] += __shfl_xor(s[qi], 1);
        s[qi] += __shfl_xor(s[qi], 2);
    }

    if (ch == 0) {
        const bool masked = (kg >= vl);
        const float L2E = 1.4426950408889634f;
        float pt[8];
        #pragma unroll
        for (int qi = 0; qi < 8; ++qi) {
            float sv = fmaf(-2.f, s[qi], Wsum);      // |score| <= ~13
            pt[qi] = masked ? 0.f : __builtin_amdgcn_exp2f(sv * L2E);
        }
        float* dst = &Pt[((size_t)b * NK + kg) * 64 + qt * 8];
        *(float4*)&dst[0] = make_float4(pt[0], pt[1], pt[2], pt[3]);
        *(float4*)&dst[4] = make_float4(pt[4], pt[5], pt[6], pt[7]);
    }
}

// ---------------------------------------------------------------------------
// pv_c: O = P.V fused with L = sum_k p and the division.
// Round-8's pv_b2 was the pipeline's biggest dispatch (60-70us, VALUBusy 9%,
// occupancy 11%): the branchy manual ring serialized ~560cyc latency per
// k-pair at 2 blocks/CU.  Fix: (1) COMPILE-TIME 512-key loop (Pt fully
// defined, p=0 for dead keys -> exact), no branches -> hipcc pipelines it;
// (2) 512 threads = (vd4 16, q 8, kp 4): k split 4-way in-block, per-thread
// serial work halves to 128 iters, 8 waves/block -> 4 waves/SIMD.
// LDS 4-way cross-kp reduce (24KB), division fused as before.
// ---------------------------------------------------------------------------
__global__ __launch_bounds__(512) void pv_c(
    const float* __restrict__ Pt,      // [B][NK][64]
    const float* __restrict__ values,  // [B][NK][256]
    float* __restrict__ out)           // [B*NQ, 256]
{
    __shared__ f32x4 red[3][8][64];
    __shared__ float Lred[4][8];

    const int bx  = blockIdx.x;
    const int b   = bx & 15;            // b in low bits: same-b blocks share XCD L2
    const int qt  = (bx >> 4) & 7;
    const int vdq = bx >> 7;            // 0..3

    const int t   = threadIdx.x;
    const int vd4 = t & 15;             // 16 float4s = 64-float V quarter
    const int q   = (t >> 4) & 7;
    const int kp4 = t >> 7;             // 0..3: k residue class

    const float* vptr = values + (size_t)b * NK * HD + vdq * 64 + vd4 * 4;
    const float* pptr = Pt + (size_t)b * NK * 64 + qt * 8 + q;

    f32x4 acc = (f32x4){0.f, 0.f, 0.f, 0.f};
    float Lacc = 0.f;
    // static trip count (NK/4 = 128), branch-free body, independent loads
    #pragma unroll 8
    for (int i = 0; i < NK / 4; ++i) {
        const int k = kp4 + 4 * i;
        float  p = pptr[(size_t)k * 64];          // broadcast across vd4 lanes
        float4 v = *(const float4*)&vptr[(size_t)k * HD];
        acc[0] = fmaf(p, v.x, acc[0]);
        acc[1] = fmaf(p, v.y, acc[1]);
        acc[2] = fmaf(p, v.z, acc[2]);
        acc[3] = fmaf(p, v.w, acc[3]);
        Lacc += p;
    }

    if (kp4 > 0) {
        red[kp4 - 1][q][vd4] = acc;
        if (vd4 == 0) Lred[kp4][q] = Lacc;
    }
    __syncthreads();
    if (kp4 == 0) {
        #pragma unroll
        for (int j = 0; j < 3; ++j) {
            f32x4 o = red[j][q][vd4];
            acc[0] += o[0]; acc[1] += o[1]; acc[2] += o[2]; acc[3] += o[3];
        }
        float L = Lacc + Lred[1][q] + Lred[2][q] + Lred[3][q];
        float r = __builtin_amdgcn_rcpf(L);
        float4 o = make_float4(acc[0] * r, acc[1] * r, acc[2] * r, acc[3] * r);
        *(float4*)&out[((size_t)(b * 64 + qt * 8 + q)) * 256 + vdq * 64 + vd4 * 4] = o;
    }
}

extern "C" void kernel_launch(void* const* d_in, const int* in_sizes, int n_in,
                              void* d_out, int out_size, void* d_ws, size_t ws_size,
                              hipStream_t stream) {
    const float* queries = (const float*)d_in[0];
    const float* keys    = (const float*)d_in[1];
    const float* values  = (const float*)d_in[2];
    const int*   vlens   = (const int*)d_in[3];
    const float* W_q     = (const float*)d_in[4];
    const float* W_k     = (const float*)d_in[5];
    const float* w_v     = (const float*)d_in[6];
    float* out = (float*)d_out;

    // ws layout (~11 MB of 256 MiB):
    float* kp = (float*)d_ws;                            // 8 MB
    float* qp = kp + (size_t)BB * NK * HD;               // 1 MB
    float* Pt = qp + (size_t)BB * NQ * HD;               // 2 MB  [B][NK][64]

    const float SC = 2.885390081777927f;                 // 2/ln(2)

    proj_fused2<<<dim3(144, 4), 256, 0, stream>>>(queries, keys, W_q, W_k,
                                                  qp, kp, SC);
    score_a2<<<dim3(128, 8), 256, 0, stream>>>(qp, kp, vlens, w_v, Pt);
    pv_c<<<dim3(512), 512, 0, stream>>>(Pt, values, out);
}